// Round 1
// baseline (330.522 us; speedup 1.0000x reference)
//
#include <hip/hip_runtime.h>
#include <math.h>

#define B_SZ   65536
#define RATE   5
#define NNEG   (B_SZ * RATE)
#define NC     100
#define NE     2048
#define GN     16
#define GP     5
#define EPSC   1e-4f

// acc layout (doubles):
// 0 sum_ce | 1 neg_cnt | 2 sum_negdist_m | 3 sum_pos_dist
// 4 cnt_wpos_to | 5 cnt_wpos_from | 6 cnt_m_to | 7 cnt_m_from | 8 margin_sum

__device__ __forceinline__ double wave_sum(double v) {
    #pragma unroll
    for (int off = 32; off > 0; off >>= 1) v += __shfl_down(v, off, 64);
    return v;
}

__device__ __forceinline__ float clip01(float x) {
    return fminf(fmaxf(x, EPSC), 1.0f);
}

// ---------------- K1: per-row argmax + max-softmax confidence ----------------
__global__ __launch_bounds__(256) void k_rowstats(
    const float* __restrict__ pred_to, const float* __restrict__ pred_from,
    float* __restrict__ conf_to, float* __restrict__ conf_from,
    unsigned char* __restrict__ am_to, unsigned char* __restrict__ am_from)
{
    int wid  = (blockIdx.x * blockDim.x + threadIdx.x) >> 6;  // one wave64 per row
    int lane = threadIdx.x & 63;
    if (wid >= 2 * B_SZ) return;
    const float* row = (wid < B_SZ) ? pred_to + (size_t)wid * NC
                                    : pred_from + (size_t)(wid - B_SZ) * NC;
    float v0 = row[lane];
    float v1 = (lane < NC - 64) ? row[64 + lane] : -INFINITY;

    float bv = v0; int bi = lane;
    if (v1 > bv) { bv = v1; bi = 64 + lane; }
    #pragma unroll
    for (int off = 32; off > 0; off >>= 1) {
        float ov = __shfl_down(bv, off, 64);
        int   oi = __shfl_down(bi, off, 64);
        if (ov > bv || (ov == bv && oi < bi)) { bv = ov; bi = oi; }
    }
    bv = __shfl(bv, 0, 64);   // broadcast max
    bi = __shfl(bi, 0, 64);   // broadcast argmax (first occurrence)

    float s = expf(v0 - bv) + ((lane < NC - 64) ? expf(v1 - bv) : 0.0f);
    #pragma unroll
    for (int off = 32; off > 0; off >>= 1) s += __shfl_down(s, off, 64);

    if (lane == 0) {
        float conf = 1.0f / s;   // max of softmax = 1 / sum(exp(x - max))
        if (wid < B_SZ) { conf_to[wid] = conf;  am_to[wid] = (unsigned char)bi; }
        else { conf_from[wid - B_SZ] = conf; am_from[wid - B_SZ] = (unsigned char)bi; }
    }
}

// ---------------- K2: negative-sample pass ----------------
__global__ __launch_bounds__(256) void k_neg(
    const int* __restrict__ perm,
    const float2* __restrict__ emb_to, const float2* __restrict__ emb_from,
    const float* __restrict__ conf_to, const float* __restrict__ conf_from,
    const unsigned char* __restrict__ am_to, const unsigned char* __restrict__ am_from,
    double* __restrict__ acc)
{
    int i = blockIdx.x * blockDim.x + threadIdx.x;
    double ce = 0.0, cnt = 0.0, dsum = 0.0;
    if (i < NNEG) {
        int jt = i / RATE;
        int jf = perm[i] / RATE;
        bool same = (am_to[jt] == am_from[jf]) && (conf_to[jt] == conf_from[jf]);
        if (!same) {
            float2 et = emb_to[jt], ef = emb_from[jf];
            float dx = et.x - ef.x, dy = et.y - ef.y;
            float d  = sqrtf(dx * dx + dy * dy);
            float q  = 1.0f / (1.0f + d * d);
            ce   = (double)(-logf(clip01(1.0f - q)));
            cnt  = 1.0;
            dsum = (double)d;
        }
    }
    ce = wave_sum(ce); cnt = wave_sum(cnt); dsum = wave_sum(dsum);
    if ((threadIdx.x & 63) == 0) {
        atomicAdd(&acc[0], ce);
        atomicAdd(&acc[1], cnt);
        atomicAdd(&acc[2], dsum);
    }
}

// ---------------- K3: positive + confidence-grid pass ----------------
__global__ __launch_bounds__(256) void k_pos(
    const int* __restrict__ idx_to, const int* __restrict__ idx_from,
    const float2* __restrict__ emb_to, const float2* __restrict__ emb_from,
    const float* __restrict__ probs,
    const int* __restrict__ error_conf,
    const float2* __restrict__ neg_grid, const float2* __restrict__ pos_grid,
    const float* __restrict__ dist_list,
    double* __restrict__ acc)
{
    __shared__ int ec[NE];
    for (int t = threadIdx.x; t < NE; t += blockDim.x) ec[t] = error_conf[t];
    __syncthreads();

    int i = blockIdx.x * blockDim.x + threadIdx.x;
    double ce = 0.0, posd = 0.0, cwt = 0.0, cwf = 0.0, cmt = 0.0, cmf = 0.0;
    if (i < B_SZ) {
        float2 et = emb_to[i], ef = emb_from[i];
        float dx = et.x - ef.x, dy = et.y - ef.y;
        float d  = sqrtf(dx * dx + dy * dy);
        posd = (double)d;
        float p = probs[i];
        float q = 1.0f / (1.0f + d * d);
        ce = (double)(-p * logf(clip01(q)) - (1.0f - p) * logf(clip01(1.0f - q)));

        int vt = idx_to[i];
        int lo = 0, hi = NE;
        while (lo < hi) { int mid = (lo + hi) >> 1; if (ec[mid] < vt) lo = mid + 1; else hi = mid; }
        int gt = (lo < NE) ? lo : NE - 1;
        bool hit_t = (ec[gt] == vt);

        int vf = idx_from[i];
        lo = 0; hi = NE;
        while (lo < hi) { int mid = (lo + hi) >> 1; if (ec[mid] < vf) lo = mid + 1; else hi = mid; }
        int gf = (lo < NE) ? lo : NE - 1;
        bool hit_f = (ec[gf] == vf);

        if (hit_t) {
            cmt = 1.0;
            double s = 0.0;
            #pragma unroll
            for (int k = 0; k < GN; ++k) {
                float2 g = neg_grid[gt * GN + k];
                float ax = et.x - g.x, ay = et.y - g.y;      // embedding_to
                float dd = sqrtf(ax * ax + ay * ay);
                float qq = 1.0f / (1.0f + dd * dd);
                s += (double)(-logf(clip01(1.0f - qq)));
            }
            ce += s;
            if (dist_list[gt] < 0.5f) {
                cwt = 1.0;
                double s2 = 0.0;
                #pragma unroll
                for (int k = 0; k < GP; ++k) {
                    float2 g = pos_grid[gt * GP + k];
                    float ax = ef.x - g.x, ay = ef.y - g.y;  // embedding_from (per reference)
                    float dd = sqrtf(ax * ax + ay * ay);
                    float qq = 1.0f / (1.0f + dd * dd);
                    s2 += (double)(-logf(clip01(qq)));
                }
                ce += s2;
            }
        }
        if (hit_f) {
            cmf = 1.0;
            double s = 0.0;
            #pragma unroll
            for (int k = 0; k < GN; ++k) {
                float2 g = neg_grid[gf * GN + k];
                float ax = ef.x - g.x, ay = ef.y - g.y;      // embedding_from
                float dd = sqrtf(ax * ax + ay * ay);
                float qq = 1.0f / (1.0f + dd * dd);
                s += (double)(-logf(clip01(1.0f - qq)));
            }
            ce += s;
            if (dist_list[gf] < 1.0f) {
                cwf = 1.0;
                double s2 = 0.0;
                #pragma unroll
                for (int k = 0; k < GP; ++k) {
                    float2 g = pos_grid[gf * GP + k];
                    float ax = ef.x - g.x, ay = ef.y - g.y;
                    float dd = sqrtf(ax * ax + ay * ay);
                    float qq = 1.0f / (1.0f + dd * dd);
                    s2 += (double)(-logf(clip01(qq)));
                }
                ce += s2;
            }
        }
    }
    ce = wave_sum(ce); posd = wave_sum(posd);
    cwt = wave_sum(cwt); cwf = wave_sum(cwf);
    cmt = wave_sum(cmt); cmf = wave_sum(cmf);
    if ((threadIdx.x & 63) == 0) {
        atomicAdd(&acc[0], ce);
        atomicAdd(&acc[3], posd);
        atomicAdd(&acc[4], cwt);
        atomicAdd(&acc[5], cwf);
        atomicAdd(&acc[6], cmt);
        atomicAdd(&acc[7], cmf);
    }
}

// ---------------- K4: margin loss pass (needs finalized means) ----------------
__global__ __launch_bounds__(256) void k_margin(
    const float2* __restrict__ emb_to, const float2* __restrict__ emb_from,
    const float* __restrict__ probs,
    const unsigned char* __restrict__ am_to, const unsigned char* __restrict__ am_from,
    double* __restrict__ acc)
{
    int i = blockIdx.x * blockDim.x + threadIdx.x;
    double ms = 0.0;
    if (i < B_SZ) {
        float pos_mean = (float)(acc[3] / (double)B_SZ);
        float neg_mean = (float)(acc[2] / fmax(acc[1], 1.0));
        float2 et = emb_to[i], ef = emb_from[i];
        float dx = et.x - ef.x, dy = et.y - ef.y;
        float d  = sqrtf(dx * dx + dy * dy);
        float p  = probs[i];
        float bm = pos_mean + (neg_mean - pos_mean) * (1.0f - p);
        float m  = (am_to[i] == am_from[i]) ? 0.0f : bm;
        ms = (double)fmaxf(m - d, 0.0f);
    }
    ms = wave_sum(ms);
    if ((threadIdx.x & 63) == 0) atomicAdd(&acc[8], ms);
}

// ---------------- K5: finalize ----------------
__global__ void k_final(const double* __restrict__ acc, float* __restrict__ out)
{
    float sum_ce  = (float)acc[0];
    float neg_cnt = (float)acc[1];
    float total_cnt = (float)B_SZ
                    + (float)GP * ((float)acc[4] + (float)acc[5])
                    + neg_cnt
                    + (float)GN * ((float)acc[6] + (float)acc[7]);
    float umap = sum_ce / fmaxf(total_cnt, 1.0f);
    if (isnan(umap)) umap = 0.0f;
    float ml = (float)(acc[8] / (double)B_SZ);
    if (isnan(ml)) ml = 0.0f;
    out[0] = umap;
    out[1] = ml;
    out[2] = umap + ml;
}

extern "C" void kernel_launch(void* const* d_in, const int* in_sizes, int n_in,
                              void* d_out, int out_size, void* d_ws, size_t ws_size,
                              hipStream_t stream)
{
    const int*   edge_to_idx   = (const int*)d_in[0];
    const int*   edge_from_idx = (const int*)d_in[1];
    const float* embedding_to  = (const float*)d_in[2];
    const float* embedding_from= (const float*)d_in[3];
    const float* probs         = (const float*)d_in[4];
    const float* pred_to       = (const float*)d_in[5];
    const float* pred_from     = (const float*)d_in[6];
    const int*   perm          = (const int*)d_in[7];
    const int*   error_conf    = (const int*)d_in[8];
    const float* neg_grid      = (const float*)d_in[9];
    const float* pos_grid      = (const float*)d_in[10];
    const float* dist_list     = (const float*)d_in[11];

    char* ws = (char*)d_ws;
    double*        acc       = (double*)ws;                        // 16 doubles
    float*         conf_to   = (float*)(ws + 128);
    float*         conf_from = conf_to + B_SZ;
    unsigned char* am_to     = (unsigned char*)(conf_from + B_SZ);
    unsigned char* am_from   = am_to + B_SZ;

    hipMemsetAsync(acc, 0, 16 * sizeof(double), stream);

    // K1: 2*B rows, one wave64 per row, 4 waves/block
    k_rowstats<<<(2 * B_SZ) / 4, 256, 0, stream>>>(
        pred_to, pred_from, conf_to, conf_from, am_to, am_from);

    k_neg<<<NNEG / 256, 256, 0, stream>>>(
        perm, (const float2*)embedding_to, (const float2*)embedding_from,
        conf_to, conf_from, am_to, am_from, acc);

    k_pos<<<B_SZ / 256, 256, 0, stream>>>(
        edge_to_idx, edge_from_idx,
        (const float2*)embedding_to, (const float2*)embedding_from,
        probs, error_conf,
        (const float2*)neg_grid, (const float2*)pos_grid, dist_list, acc);

    k_margin<<<B_SZ / 256, 256, 0, stream>>>(
        (const float2*)embedding_to, (const float2*)embedding_from,
        probs, am_to, am_from, acc);

    k_final<<<1, 1, 0, stream>>>(acc, (float*)d_out);
}

// Round 2
// 72.237 us; speedup vs baseline: 4.5755x; 4.5755x over previous
//
#include <hip/hip_runtime.h>
#include <math.h>

#define B_SZ   65536
#define RATE   5
#define NNEG   (B_SZ * RATE)
#define NC     100
#define NE     2048
#define GN     16
#define GP     5
#define EPSC   1e-4f

#define NB_NEG 1280   // NNEG/256
#define NB_POS 256    // B_SZ/256
#define NB_MAR 256

// acc layout (doubles):
// 0 sum_ce | 1 neg_cnt | 2 sum_negdist_m | 3 sum_pos_dist
// 4 cnt_wpos_to | 5 cnt_wpos_from | 6 cnt_m_to | 7 cnt_m_from

__device__ __forceinline__ double wave_sum(double v) {
    #pragma unroll
    for (int off = 32; off > 0; off >>= 1) v += __shfl_down(v, off, 64);
    return v;
}

__device__ __forceinline__ float clip01(float x) {
    return fminf(fmaxf(x, EPSC), 1.0f);
}

// ---------------- K1: per-row argmax + max-softmax confidence ----------------
__global__ __launch_bounds__(256) void k_rowstats(
    const float* __restrict__ pred_to, const float* __restrict__ pred_from,
    float* __restrict__ conf_to, float* __restrict__ conf_from,
    unsigned char* __restrict__ am_to, unsigned char* __restrict__ am_from)
{
    int wid  = (blockIdx.x * blockDim.x + threadIdx.x) >> 6;  // one wave64 per row
    int lane = threadIdx.x & 63;
    if (wid >= 2 * B_SZ) return;
    const float* row = (wid < B_SZ) ? pred_to + (size_t)wid * NC
                                    : pred_from + (size_t)(wid - B_SZ) * NC;
    float v0 = row[lane];
    float v1 = (lane < NC - 64) ? row[64 + lane] : -INFINITY;

    float bv = v0; int bi = lane;
    if (v1 > bv) { bv = v1; bi = 64 + lane; }
    #pragma unroll
    for (int off = 32; off > 0; off >>= 1) {
        float ov = __shfl_down(bv, off, 64);
        int   oi = __shfl_down(bi, off, 64);
        if (ov > bv || (ov == bv && oi < bi)) { bv = ov; bi = oi; }
    }
    bv = __shfl(bv, 0, 64);   // broadcast max
    bi = __shfl(bi, 0, 64);   // broadcast argmax (first occurrence)

    float s = expf(v0 - bv) + ((lane < NC - 64) ? expf(v1 - bv) : 0.0f);
    #pragma unroll
    for (int off = 32; off > 0; off >>= 1) s += __shfl_down(s, off, 64);

    if (lane == 0) {
        float conf = 1.0f / s;   // max of softmax = 1 / sum(exp(x - max))
        if (wid < B_SZ) { conf_to[wid] = conf;  am_to[wid] = (unsigned char)bi; }
        else { conf_from[wid - B_SZ] = conf; am_from[wid - B_SZ] = (unsigned char)bi; }
    }
}

// ---------------- K2: negative-sample pass (per-block partials) ----------------
__global__ __launch_bounds__(256) void k_neg(
    const int* __restrict__ perm,
    const float2* __restrict__ emb_to, const float2* __restrict__ emb_from,
    const float* __restrict__ conf_to, const float* __restrict__ conf_from,
    const unsigned char* __restrict__ am_to, const unsigned char* __restrict__ am_from,
    double* __restrict__ pneg)
{
    int i = blockIdx.x * blockDim.x + threadIdx.x;
    double ce = 0.0, cnt = 0.0, dsum = 0.0;
    {
        int jt = i / RATE;
        int jf = perm[i] / RATE;
        bool same = (am_to[jt] == am_from[jf]) && (conf_to[jt] == conf_from[jf]);
        if (!same) {
            float2 et = emb_to[jt], ef = emb_from[jf];
            float dx = et.x - ef.x, dy = et.y - ef.y;
            float d  = sqrtf(dx * dx + dy * dy);
            float q  = 1.0f / (1.0f + d * d);
            ce   = (double)(-logf(clip01(1.0f - q)));
            cnt  = 1.0;
            dsum = (double)d;
        }
    }
    ce = wave_sum(ce); cnt = wave_sum(cnt); dsum = wave_sum(dsum);
    __shared__ double sr[3][4];
    int w = threadIdx.x >> 6;
    if ((threadIdx.x & 63) == 0) { sr[0][w] = ce; sr[1][w] = cnt; sr[2][w] = dsum; }
    __syncthreads();
    if (threadIdx.x == 0) {
        pneg[blockIdx.x * 3 + 0] = sr[0][0] + sr[0][1] + sr[0][2] + sr[0][3];
        pneg[blockIdx.x * 3 + 1] = sr[1][0] + sr[1][1] + sr[1][2] + sr[1][3];
        pneg[blockIdx.x * 3 + 2] = sr[2][0] + sr[2][1] + sr[2][2] + sr[2][3];
    }
}

// ---------------- K3: positive + confidence-grid pass (per-block partials) ----
__global__ __launch_bounds__(256) void k_pos(
    const int* __restrict__ idx_to, const int* __restrict__ idx_from,
    const float2* __restrict__ emb_to, const float2* __restrict__ emb_from,
    const float* __restrict__ probs,
    const int* __restrict__ error_conf,
    const float2* __restrict__ neg_grid, const float2* __restrict__ pos_grid,
    const float* __restrict__ dist_list,
    double* __restrict__ ppos)
{
    __shared__ int ec[NE];
    for (int t = threadIdx.x; t < NE; t += blockDim.x) ec[t] = error_conf[t];
    __syncthreads();

    int i = blockIdx.x * blockDim.x + threadIdx.x;
    double v[6] = {0, 0, 0, 0, 0, 0};   // ce, posd, cwt, cwf, cmt, cmf
    {
        float2 et = emb_to[i], ef = emb_from[i];
        float dx = et.x - ef.x, dy = et.y - ef.y;
        float d  = sqrtf(dx * dx + dy * dy);
        v[1] = (double)d;
        float p = probs[i];
        float q = 1.0f / (1.0f + d * d);
        double ce = (double)(-p * logf(clip01(q)) - (1.0f - p) * logf(clip01(1.0f - q)));

        int vt = idx_to[i];
        int lo = 0, hi = NE;
        while (lo < hi) { int mid = (lo + hi) >> 1; if (ec[mid] < vt) lo = mid + 1; else hi = mid; }
        int gt = (lo < NE) ? lo : NE - 1;
        bool hit_t = (ec[gt] == vt);

        int vf = idx_from[i];
        lo = 0; hi = NE;
        while (lo < hi) { int mid = (lo + hi) >> 1; if (ec[mid] < vf) lo = mid + 1; else hi = mid; }
        int gf = (lo < NE) ? lo : NE - 1;
        bool hit_f = (ec[gf] == vf);

        if (hit_t) {
            v[4] = 1.0;
            double s = 0.0;
            #pragma unroll
            for (int k = 0; k < GN; ++k) {
                float2 g = neg_grid[gt * GN + k];
                float ax = et.x - g.x, ay = et.y - g.y;      // embedding_to
                float dd = sqrtf(ax * ax + ay * ay);
                float qq = 1.0f / (1.0f + dd * dd);
                s += (double)(-logf(clip01(1.0f - qq)));
            }
            ce += s;
            if (dist_list[gt] < 0.5f) {
                v[2] = 1.0;
                double s2 = 0.0;
                #pragma unroll
                for (int k = 0; k < GP; ++k) {
                    float2 g = pos_grid[gt * GP + k];
                    float ax = ef.x - g.x, ay = ef.y - g.y;  // embedding_from (per reference)
                    float dd = sqrtf(ax * ax + ay * ay);
                    float qq = 1.0f / (1.0f + dd * dd);
                    s2 += (double)(-logf(clip01(qq)));
                }
                ce += s2;
            }
        }
        if (hit_f) {
            v[5] = 1.0;
            double s = 0.0;
            #pragma unroll
            for (int k = 0; k < GN; ++k) {
                float2 g = neg_grid[gf * GN + k];
                float ax = ef.x - g.x, ay = ef.y - g.y;      // embedding_from
                float dd = sqrtf(ax * ax + ay * ay);
                float qq = 1.0f / (1.0f + dd * dd);
                s += (double)(-logf(clip01(1.0f - qq)));
            }
            ce += s;
            if (dist_list[gf] < 1.0f) {
                v[3] = 1.0;
                double s2 = 0.0;
                #pragma unroll
                for (int k = 0; k < GP; ++k) {
                    float2 g = pos_grid[gf * GP + k];
                    float ax = ef.x - g.x, ay = ef.y - g.y;
                    float dd = sqrtf(ax * ax + ay * ay);
                    float qq = 1.0f / (1.0f + dd * dd);
                    s2 += (double)(-logf(clip01(qq)));
                }
                ce += s2;
            }
        }
        v[0] = ce;
    }
    __shared__ double sr[6][4];
    int w = threadIdx.x >> 6;
    #pragma unroll
    for (int j = 0; j < 6; ++j) {
        double r = wave_sum(v[j]);
        if ((threadIdx.x & 63) == 0) sr[j][w] = r;
    }
    __syncthreads();
    if (threadIdx.x < 6) {
        int j = threadIdx.x;
        ppos[blockIdx.x * 6 + j] = sr[j][0] + sr[j][1] + sr[j][2] + sr[j][3];
    }
}

// ---------------- K4: fold partials into acc (single wave) ----------------
__global__ __launch_bounds__(64) void k_reduce1(
    const double* __restrict__ pneg, const double* __restrict__ ppos,
    double* __restrict__ acc)
{
    int lane = threadIdx.x;
    double ce = 0.0, cnt = 0.0, dsum = 0.0;
    for (int b = lane; b < NB_NEG; b += 64) {
        ce   += pneg[b * 3 + 0];
        cnt  += pneg[b * 3 + 1];
        dsum += pneg[b * 3 + 2];
    }
    double pv[6] = {0, 0, 0, 0, 0, 0};
    for (int b = lane; b < NB_POS; b += 64) {
        #pragma unroll
        for (int j = 0; j < 6; ++j) pv[j] += ppos[b * 6 + j];
    }
    ce   = wave_sum(ce);
    cnt  = wave_sum(cnt);
    dsum = wave_sum(dsum);
    #pragma unroll
    for (int j = 0; j < 6; ++j) pv[j] = wave_sum(pv[j]);
    if (lane == 0) {
        acc[0] = ce + pv[0];
        acc[1] = cnt;
        acc[2] = dsum;
        acc[3] = pv[1];
        acc[4] = pv[2];
        acc[5] = pv[3];
        acc[6] = pv[4];
        acc[7] = pv[5];
    }
}

// ---------------- K5: margin loss pass (per-block partials) ----------------
__global__ __launch_bounds__(256) void k_margin(
    const float2* __restrict__ emb_to, const float2* __restrict__ emb_from,
    const float* __restrict__ probs,
    const unsigned char* __restrict__ am_to, const unsigned char* __restrict__ am_from,
    const double* __restrict__ acc,
    double* __restrict__ pmar)
{
    int i = blockIdx.x * blockDim.x + threadIdx.x;
    float pos_mean = (float)(acc[3] / (double)B_SZ);
    float neg_mean = (float)(acc[2] / fmax(acc[1], 1.0));
    double ms;
    {
        float2 et = emb_to[i], ef = emb_from[i];
        float dx = et.x - ef.x, dy = et.y - ef.y;
        float d  = sqrtf(dx * dx + dy * dy);
        float p  = probs[i];
        float bm = pos_mean + (neg_mean - pos_mean) * (1.0f - p);
        float m  = (am_to[i] == am_from[i]) ? 0.0f : bm;
        ms = (double)fmaxf(m - d, 0.0f);
    }
    ms = wave_sum(ms);
    __shared__ double sr[4];
    int w = threadIdx.x >> 6;
    if ((threadIdx.x & 63) == 0) sr[w] = ms;
    __syncthreads();
    if (threadIdx.x == 0) pmar[blockIdx.x] = sr[0] + sr[1] + sr[2] + sr[3];
}

// ---------------- K6: finalize (single wave) ----------------
__global__ __launch_bounds__(64) void k_final(
    const double* __restrict__ acc, const double* __restrict__ pmar,
    float* __restrict__ out)
{
    int lane = threadIdx.x;
    double ms = 0.0;
    for (int b = lane; b < NB_MAR; b += 64) ms += pmar[b];
    ms = wave_sum(ms);
    if (lane == 0) {
        float sum_ce  = (float)acc[0];
        float neg_cnt = (float)acc[1];
        float total_cnt = (float)B_SZ
                        + (float)GP * ((float)acc[4] + (float)acc[5])
                        + neg_cnt
                        + (float)GN * ((float)acc[6] + (float)acc[7]);
        float umap = sum_ce / fmaxf(total_cnt, 1.0f);
        if (isnan(umap)) umap = 0.0f;
        float ml = (float)(ms / (double)B_SZ);
        if (isnan(ml)) ml = 0.0f;
        out[0] = umap;
        out[1] = ml;
        out[2] = umap + ml;
    }
}

extern "C" void kernel_launch(void* const* d_in, const int* in_sizes, int n_in,
                              void* d_out, int out_size, void* d_ws, size_t ws_size,
                              hipStream_t stream)
{
    const int*   edge_to_idx   = (const int*)d_in[0];
    const int*   edge_from_idx = (const int*)d_in[1];
    const float* embedding_to  = (const float*)d_in[2];
    const float* embedding_from= (const float*)d_in[3];
    const float* probs         = (const float*)d_in[4];
    const float* pred_to       = (const float*)d_in[5];
    const float* pred_from     = (const float*)d_in[6];
    const int*   perm          = (const int*)d_in[7];
    const int*   error_conf    = (const int*)d_in[8];
    const float* neg_grid      = (const float*)d_in[9];
    const float* pos_grid      = (const float*)d_in[10];
    const float* dist_list     = (const float*)d_in[11];

    char* ws = (char*)d_ws;
    double*        acc       = (double*)ws;                        // 16 doubles
    float*         conf_to   = (float*)(ws + 128);
    float*         conf_from = conf_to + B_SZ;
    unsigned char* am_to     = (unsigned char*)(conf_from + B_SZ);
    unsigned char* am_from   = am_to + B_SZ;
    double*        pneg      = (double*)(am_from + B_SZ);          // NB_NEG*3
    double*        ppos      = pneg + NB_NEG * 3;                  // NB_POS*6
    double*        pmar      = ppos + NB_POS * 6;                  // NB_MAR

    // K1: 2*B rows, one wave64 per row, 4 waves/block
    k_rowstats<<<(2 * B_SZ) / 4, 256, 0, stream>>>(
        pred_to, pred_from, conf_to, conf_from, am_to, am_from);

    k_neg<<<NB_NEG, 256, 0, stream>>>(
        perm, (const float2*)embedding_to, (const float2*)embedding_from,
        conf_to, conf_from, am_to, am_from, pneg);

    k_pos<<<NB_POS, 256, 0, stream>>>(
        edge_to_idx, edge_from_idx,
        (const float2*)embedding_to, (const float2*)embedding_from,
        probs, error_conf,
        (const float2*)neg_grid, (const float2*)pos_grid, dist_list, ppos);

    k_reduce1<<<1, 64, 0, stream>>>(pneg, ppos, acc);

    k_margin<<<NB_MAR, 256, 0, stream>>>(
        (const float2*)embedding_to, (const float2*)embedding_from,
        probs, am_to, am_from, acc, pmar);

    k_final<<<1, 64, 0, stream>>>(acc, pmar, (float*)d_out);
}

// Round 3
// 48.480 us; speedup vs baseline: 6.8176x; 1.4900x over previous
//
#include <hip/hip_runtime.h>
#include <math.h>

#define B_SZ   65536
#define RATE   5
#define NNEG   (B_SZ * RATE)
#define NC     100
#define NE     2048
#define GN     16
#define GP     5
#define EPSC   1e-4f

#define NB_NEG 1280   // NNEG/256
#define NB_POS 256    // B_SZ/256
#define NB_MAR 256

// acc layout (doubles):
// 0 sum_ce | 1 neg_cnt | 2 sum_negdist_m | 3 sum_pos_dist
// 4 cnt_wpos_to | 5 cnt_wpos_from | 6 cnt_m_to | 7 cnt_m_from

__device__ __forceinline__ double wave_sum(double v) {
    #pragma unroll
    for (int off = 32; off > 0; off >>= 1) v += __shfl_down(v, off, 64);
    return v;
}

__device__ __forceinline__ float clip01(float x) {
    return fminf(fmaxf(x, EPSC), 1.0f);
}

// ---------------- K1: per-row argmax + max-softmax confidence ----------------
// One LANE per row: row held in registers, zero cross-lane ops.
__global__ __launch_bounds__(256, 2) void k_rowstats(
    const float* __restrict__ pred_to, const float* __restrict__ pred_from,
    float* __restrict__ conf_to, float* __restrict__ conf_from,
    unsigned char* __restrict__ am_to, unsigned char* __restrict__ am_from)
{
    int i = blockIdx.x * blockDim.x + threadIdx.x;   // 0 .. 2*B_SZ-1
    const float* row = (i < B_SZ) ? pred_to + (size_t)i * NC
                                  : pred_from + (size_t)(i - B_SZ) * NC;
    const float4* r4 = (const float4*)row;
    float4 v[25];
    #pragma unroll
    for (int t = 0; t < 25; ++t) v[t] = r4[t];

    // pass 1: max
    float m = -INFINITY;
    #pragma unroll
    for (int t = 0; t < 25; ++t)
        m = fmaxf(m, fmaxf(fmaxf(v[t].x, v[t].y), fmaxf(v[t].z, v[t].w)));

    // pass 2: first index of max + sum of exp(x - max)
    int bi = NC;
    float s = 0.0f;
    #pragma unroll
    for (int t = 0; t < 25; ++t) {
        float e0 = v[t].x, e1 = v[t].y, e2 = v[t].z, e3 = v[t].w;
        if (e0 == m) bi = min(bi, 4 * t + 0);
        if (e1 == m) bi = min(bi, 4 * t + 1);
        if (e2 == m) bi = min(bi, 4 * t + 2);
        if (e3 == m) bi = min(bi, 4 * t + 3);
        s += expf(e0 - m) + expf(e1 - m) + expf(e2 - m) + expf(e3 - m);
    }
    float conf = 1.0f / s;   // max of softmax = 1 / sum(exp(x - max))
    if (i < B_SZ) { conf_to[i] = conf;  am_to[i] = (unsigned char)bi; }
    else { conf_from[i - B_SZ] = conf; am_from[i - B_SZ] = (unsigned char)bi; }
}

// ---------------- K2: fused negative-sample + positive/grid pass -------------
__global__ __launch_bounds__(256) void k_negpos(
    const int* __restrict__ perm,
    const float2* __restrict__ emb_to, const float2* __restrict__ emb_from,
    const float* __restrict__ conf_to, const float* __restrict__ conf_from,
    const unsigned char* __restrict__ am_to, const unsigned char* __restrict__ am_from,
    const int* __restrict__ idx_to, const int* __restrict__ idx_from,
    const float* __restrict__ probs,
    const int* __restrict__ error_conf,
    const float2* __restrict__ neg_grid, const float2* __restrict__ pos_grid,
    const float* __restrict__ dist_list,
    double* __restrict__ pneg, double* __restrict__ ppos)
{
    if (blockIdx.x < NB_NEG) {
        // ---- negative-sample path ----
        int i = blockIdx.x * blockDim.x + threadIdx.x;
        double ce = 0.0, cnt = 0.0, dsum = 0.0;
        {
            int jt = i / RATE;
            int jf = perm[i] / RATE;
            bool same = (am_to[jt] == am_from[jf]) && (conf_to[jt] == conf_from[jf]);
            if (!same) {
                float2 et = emb_to[jt], ef = emb_from[jf];
                float dx = et.x - ef.x, dy = et.y - ef.y;
                float d  = sqrtf(dx * dx + dy * dy);
                float q  = 1.0f / (1.0f + d * d);
                ce   = (double)(-logf(clip01(1.0f - q)));
                cnt  = 1.0;
                dsum = (double)d;
            }
        }
        ce = wave_sum(ce); cnt = wave_sum(cnt); dsum = wave_sum(dsum);
        __shared__ double sr[3][4];
        int w = threadIdx.x >> 6;
        if ((threadIdx.x & 63) == 0) { sr[0][w] = ce; sr[1][w] = cnt; sr[2][w] = dsum; }
        __syncthreads();
        if (threadIdx.x == 0) {
            pneg[blockIdx.x * 3 + 0] = sr[0][0] + sr[0][1] + sr[0][2] + sr[0][3];
            pneg[blockIdx.x * 3 + 1] = sr[1][0] + sr[1][1] + sr[1][2] + sr[1][3];
            pneg[blockIdx.x * 3 + 2] = sr[2][0] + sr[2][1] + sr[2][2] + sr[2][3];
        }
    } else {
        // ---- positive + confidence-grid path ----
        int blk = blockIdx.x - NB_NEG;
        __shared__ int ec[NE];
        for (int t = threadIdx.x; t < NE; t += blockDim.x) ec[t] = error_conf[t];
        __syncthreads();

        int i = blk * blockDim.x + threadIdx.x;
        double v[6] = {0, 0, 0, 0, 0, 0};   // ce, posd, cwt, cwf, cmt, cmf
        {
            float2 et = emb_to[i], ef = emb_from[i];
            float dx = et.x - ef.x, dy = et.y - ef.y;
            float d  = sqrtf(dx * dx + dy * dy);
            v[1] = (double)d;
            float p = probs[i];
            float q = 1.0f / (1.0f + d * d);
            double ce = (double)(-p * logf(clip01(q)) - (1.0f - p) * logf(clip01(1.0f - q)));

            int vt = idx_to[i];
            int lo = 0, hi = NE;
            while (lo < hi) { int mid = (lo + hi) >> 1; if (ec[mid] < vt) lo = mid + 1; else hi = mid; }
            int gt = (lo < NE) ? lo : NE - 1;
            bool hit_t = (ec[gt] == vt);

            int vf = idx_from[i];
            lo = 0; hi = NE;
            while (lo < hi) { int mid = (lo + hi) >> 1; if (ec[mid] < vf) lo = mid + 1; else hi = mid; }
            int gf = (lo < NE) ? lo : NE - 1;
            bool hit_f = (ec[gf] == vf);

            if (hit_t) {
                v[4] = 1.0;
                double s = 0.0;
                #pragma unroll
                for (int k = 0; k < GN; ++k) {
                    float2 g = neg_grid[gt * GN + k];
                    float ax = et.x - g.x, ay = et.y - g.y;      // embedding_to
                    float dd = sqrtf(ax * ax + ay * ay);
                    float qq = 1.0f / (1.0f + dd * dd);
                    s += (double)(-logf(clip01(1.0f - qq)));
                }
                ce += s;
                if (dist_list[gt] < 0.5f) {
                    v[2] = 1.0;
                    double s2 = 0.0;
                    #pragma unroll
                    for (int k = 0; k < GP; ++k) {
                        float2 g = pos_grid[gt * GP + k];
                        float ax = ef.x - g.x, ay = ef.y - g.y;  // embedding_from (per reference)
                        float dd = sqrtf(ax * ax + ay * ay);
                        float qq = 1.0f / (1.0f + dd * dd);
                        s2 += (double)(-logf(clip01(qq)));
                    }
                    ce += s2;
                }
            }
            if (hit_f) {
                v[5] = 1.0;
                double s = 0.0;
                #pragma unroll
                for (int k = 0; k < GN; ++k) {
                    float2 g = neg_grid[gf * GN + k];
                    float ax = ef.x - g.x, ay = ef.y - g.y;      // embedding_from
                    float dd = sqrtf(ax * ax + ay * ay);
                    float qq = 1.0f / (1.0f + dd * dd);
                    s += (double)(-logf(clip01(1.0f - qq)));
                }
                ce += s;
                if (dist_list[gf] < 1.0f) {
                    v[3] = 1.0;
                    double s2 = 0.0;
                    #pragma unroll
                    for (int k = 0; k < GP; ++k) {
                        float2 g = pos_grid[gf * GP + k];
                        float ax = ef.x - g.x, ay = ef.y - g.y;
                        float dd = sqrtf(ax * ax + ay * ay);
                        float qq = 1.0f / (1.0f + dd * dd);
                        s2 += (double)(-logf(clip01(qq)));
                    }
                    ce += s2;
                }
            }
            v[0] = ce;
        }
        __shared__ double sr2[6][4];
        int w = threadIdx.x >> 6;
        #pragma unroll
        for (int j = 0; j < 6; ++j) {
            double r = wave_sum(v[j]);
            if ((threadIdx.x & 63) == 0) sr2[j][w] = r;
        }
        __syncthreads();
        if (threadIdx.x < 6) {
            int j = threadIdx.x;
            ppos[blk * 6 + j] = sr2[j][0] + sr2[j][1] + sr2[j][2] + sr2[j][3];
        }
    }
}

// ---------------- K3: fold partials into acc (single wave) ----------------
__global__ __launch_bounds__(64) void k_reduce1(
    const double* __restrict__ pneg, const double* __restrict__ ppos,
    double* __restrict__ acc)
{
    int lane = threadIdx.x;
    double ce = 0.0, cnt = 0.0, dsum = 0.0;
    for (int b = lane; b < NB_NEG; b += 64) {
        ce   += pneg[b * 3 + 0];
        cnt  += pneg[b * 3 + 1];
        dsum += pneg[b * 3 + 2];
    }
    double pv[6] = {0, 0, 0, 0, 0, 0};
    for (int b = lane; b < NB_POS; b += 64) {
        #pragma unroll
        for (int j = 0; j < 6; ++j) pv[j] += ppos[b * 6 + j];
    }
    ce   = wave_sum(ce);
    cnt  = wave_sum(cnt);
    dsum = wave_sum(dsum);
    #pragma unroll
    for (int j = 0; j < 6; ++j) pv[j] = wave_sum(pv[j]);
    if (lane == 0) {
        acc[0] = ce + pv[0];
        acc[1] = cnt;
        acc[2] = dsum;
        acc[3] = pv[1];
        acc[4] = pv[2];
        acc[5] = pv[3];
        acc[6] = pv[4];
        acc[7] = pv[5];
    }
}

// ---------------- K4: margin loss pass (per-block partials) ----------------
__global__ __launch_bounds__(256) void k_margin(
    const float2* __restrict__ emb_to, const float2* __restrict__ emb_from,
    const float* __restrict__ probs,
    const unsigned char* __restrict__ am_to, const unsigned char* __restrict__ am_from,
    const double* __restrict__ acc,
    double* __restrict__ pmar)
{
    int i = blockIdx.x * blockDim.x + threadIdx.x;
    float pos_mean = (float)(acc[3] / (double)B_SZ);
    float neg_mean = (float)(acc[2] / fmax(acc[1], 1.0));
    double ms;
    {
        float2 et = emb_to[i], ef = emb_from[i];
        float dx = et.x - ef.x, dy = et.y - ef.y;
        float d  = sqrtf(dx * dx + dy * dy);
        float p  = probs[i];
        float bm = pos_mean + (neg_mean - pos_mean) * (1.0f - p);
        float m  = (am_to[i] == am_from[i]) ? 0.0f : bm;
        ms = (double)fmaxf(m - d, 0.0f);
    }
    ms = wave_sum(ms);
    __shared__ double sr[4];
    int w = threadIdx.x >> 6;
    if ((threadIdx.x & 63) == 0) sr[w] = ms;
    __syncthreads();
    if (threadIdx.x == 0) pmar[blockIdx.x] = sr[0] + sr[1] + sr[2] + sr[3];
}

// ---------------- K5: finalize (single wave) ----------------
__global__ __launch_bounds__(64) void k_final(
    const double* __restrict__ acc, const double* __restrict__ pmar,
    float* __restrict__ out)
{
    int lane = threadIdx.x;
    double ms = 0.0;
    for (int b = lane; b < NB_MAR; b += 64) ms += pmar[b];
    ms = wave_sum(ms);
    if (lane == 0) {
        float sum_ce  = (float)acc[0];
        float neg_cnt = (float)acc[1];
        float total_cnt = (float)B_SZ
                        + (float)GP * ((float)acc[4] + (float)acc[5])
                        + neg_cnt
                        + (float)GN * ((float)acc[6] + (float)acc[7]);
        float umap = sum_ce / fmaxf(total_cnt, 1.0f);
        if (isnan(umap)) umap = 0.0f;
        float ml = (float)(ms / (double)B_SZ);
        if (isnan(ml)) ml = 0.0f;
        out[0] = umap;
        out[1] = ml;
        out[2] = umap + ml;
    }
}

extern "C" void kernel_launch(void* const* d_in, const int* in_sizes, int n_in,
                              void* d_out, int out_size, void* d_ws, size_t ws_size,
                              hipStream_t stream)
{
    const int*   edge_to_idx   = (const int*)d_in[0];
    const int*   edge_from_idx = (const int*)d_in[1];
    const float* embedding_to  = (const float*)d_in[2];
    const float* embedding_from= (const float*)d_in[3];
    const float* probs         = (const float*)d_in[4];
    const float* pred_to       = (const float*)d_in[5];
    const float* pred_from     = (const float*)d_in[6];
    const int*   perm          = (const int*)d_in[7];
    const int*   error_conf    = (const int*)d_in[8];
    const float* neg_grid      = (const float*)d_in[9];
    const float* pos_grid      = (const float*)d_in[10];
    const float* dist_list     = (const float*)d_in[11];

    char* ws = (char*)d_ws;
    double*        acc       = (double*)ws;                        // 16 doubles
    float*         conf_to   = (float*)(ws + 128);
    float*         conf_from = conf_to + B_SZ;
    unsigned char* am_to     = (unsigned char*)(conf_from + B_SZ);
    unsigned char* am_from   = am_to + B_SZ;
    double*        pneg      = (double*)(am_from + B_SZ);          // NB_NEG*3
    double*        ppos      = pneg + NB_NEG * 3;                  // NB_POS*6
    double*        pmar      = ppos + NB_POS * 6;                  // NB_MAR

    // K1: one lane per row, 512 blocks x 256
    k_rowstats<<<(2 * B_SZ) / 256, 256, 0, stream>>>(
        pred_to, pred_from, conf_to, conf_from, am_to, am_from);

    // K2: fused neg + pos
    k_negpos<<<NB_NEG + NB_POS, 256, 0, stream>>>(
        perm, (const float2*)embedding_to, (const float2*)embedding_from,
        conf_to, conf_from, am_to, am_from,
        edge_to_idx, edge_from_idx, probs, error_conf,
        (const float2*)neg_grid, (const float2*)pos_grid, dist_list,
        pneg, ppos);

    k_reduce1<<<1, 64, 0, stream>>>(pneg, ppos, acc);

    k_margin<<<NB_MAR, 256, 0, stream>>>(
        (const float2*)embedding_to, (const float2*)embedding_from,
        probs, am_to, am_from, acc, pmar);

    k_final<<<1, 64, 0, stream>>>(acc, pmar, (float*)d_out);
}